// Round 8
// baseline (257.306 us; speedup 1.0000x reference)
//
#include <hip/hip_runtime.h>

// ClauseInferModule: C=16, B=64, G=2048, S=8, L=4, 3 steps. SINGLE fused kernel.
// w-units: w = v*(1000/ln2) => exp((a-b)/gamma)==exp2(wa-wb), gamma*ln==log2 EXACT.
// Native v_exp_f32/v_log_f32 (round-7: libm transcendentals were the VALU bottleneck).
//
// Grid 256 blocks x 1024 threads, block=(c, bchunk 8, ghalf). Residency PROVABLY
// guaranteed: <=2 blocks fit per CU on every resource, 256 blocks <= capacity under
// any packing -> custom spin barriers cannot deadlock.
// Per step (all inside one launch):
//   clause: 4 rows b-interleaved in LDS (lds4[g] = b-quad), one ds_read_b128
//     gathers a literal for 4 b's; softand_L + two-pass softor_S, all native.
//     q stays in REGISTERS. I indices register-cached ONCE for all 3 steps.
//   m2: block max -> device atomicMax -> per-clause 16-block arrival spin
//     (round-6-proven pattern).
//   merge: s3 = softor2(own staged quad, q/max(m2,1)) from registers;
//     steps 0,1 write w-units R to ws; step 2 keeps s3 in registers.
//   m3: block max -> device atomicMax -> 256-block arrival spin with
//     __threadfence release/acquire (data-passing pattern validated round 3).
// Final output write fused: out = s3 * RKF/max(m3*RKF, 1)  (w -> real).
// softand renorm provably no-op (R<=1 invariant => softand<1 strictly).
// where(m>1,s/m,s) == s/max(m,1) exactly.

namespace {
constexpr int C = 16, B = 64, G = 2048, S = 8, L = 4;
constexpr int STEPS = 3;
constexpr int N  = C * B * G;
constexpr float KF  = 1442.6950408889634f;    // 1000/ln2 : real -> w
constexpr float RKF = 6.9314718055994531e-4f; // ln2/1000 : w -> real
}

__device__ __forceinline__ float ex2(float v) { return __builtin_amdgcn_exp2f(v); } // v_exp_f32
__device__ __forceinline__ float lg2(float v) { return __builtin_amdgcn_logf(v); }  // v_log_f32

__device__ __forceinline__ unsigned f2key(float f) {
    unsigned b = __float_as_uint(f);
    return (b & 0x80000000u) ? ~b : (b | 0x80000000u);
}
__device__ __forceinline__ float key2f(unsigned k) {
    return (k & 0x80000000u) ? __uint_as_float(k & 0x7fffffffu)
                             : __uint_as_float(~k);
}
__device__ __forceinline__ float4 f4min(float4 a, float4 b) {
    return make_float4(fminf(a.x,b.x), fminf(a.y,b.y), fminf(a.z,b.z), fminf(a.w,b.w));
}
__device__ __forceinline__ float4 f4max(float4 a, float4 b) {
    return make_float4(fmaxf(a.x,b.x), fmaxf(a.y,b.y), fmaxf(a.z,b.z), fmaxf(a.w,b.w));
}
__device__ __forceinline__ float4 f4e(float4 m, float4 v) {   // exp2(m - v), native
    return make_float4(ex2(m.x-v.x), ex2(m.y-v.y), ex2(m.z-v.z), ex2(m.w-v.w));
}
__device__ __forceinline__ float4 f4add(float4 a, float4 b) {
    return make_float4(a.x+b.x, a.y+b.y, a.z+b.z, a.w+b.w);
}

// mk layout (uints): [0..47] m2[step][c] | [48..50] m3[step] |
//                    [64..111] arr16[step][c] | [112..114] arr256[step]

__global__ __launch_bounds__(1024, 4) void k_all(const float* __restrict__ x,
                                                 const int* __restrict__ I,
                                                 float* R,            // ws intermediate (w-units)
                                                 float* outp,         // d_out (real units)
                                                 unsigned* mk) {
    __shared__ float4 lds4[G];        // 32 KB: 4 rows b-interleaved, w-units scaled
    __shared__ float wred[16];
    __shared__ float shv;

    const int blk = blockIdx.x, tid = threadIdx.x;
    const int c = blk >> 4, bchunk = (blk >> 1) & 7, ghalf = blk & 1;
    const int g = ghalf * 1024 + tid, b0 = bchunk * 8;

    // I indices register-cached once for all 3 steps (b-independent)
    const int4* Ib = (const int4*)(I + (size_t)(c * G + g) * (S * L));
    int4 ix[S];
#pragma unroll
    for (int s = 0; s < S; ++s) ix[s] = Ib[s];

    unsigned* m2k  = mk;
    unsigned* m3k  = mk + 48;
    unsigned* a16  = mk + 64;
    unsigned* a256 = mk + 112;

    float ss = KF;                    // step0: real->w; later: m3 renorm scale
    float s3r[8];

    for (int step = 0; step < STEPS; ++step) {
        const float* srcp = step ? R : x;
        const int rb = step ? (c * B + b0) : b0;   // step0 broadcasts x over c

        // preload group-0 rows: 4 rows, one float2 column per thread
        float2 pa[4];
#pragma unroll
        for (int j = 0; j < 4; ++j)
            pa[j] = ((const float2*)(srcp + (size_t)(rb + j) * G))[tid];

        float4 qv[2], sq[2];
        float lmax = -3.0e38f;
#pragma unroll
        for (int grp = 0; grp < 2; ++grp) {
            if (grp) __syncthreads();             // prior group's gathers done
            lds4[2*tid]   = make_float4(pa[0].x*ss, pa[1].x*ss, pa[2].x*ss, pa[3].x*ss);
            lds4[2*tid+1] = make_float4(pa[0].y*ss, pa[1].y*ss, pa[2].y*ss, pa[3].y*ss);
            if (grp == 0) {                       // prefetch group-1 rows
#pragma unroll
                for (int j = 0; j < 4; ++j)
                    pa[j] = ((const float2*)(srcp + (size_t)(rb + 4 + j) * G))[tid];
            }
            __syncthreads();                      // staging visible

            sq[grp] = lds4[g];                    // own src b-quad for merge

            // softand over L (component-wise on b-quad), two-pass softor over S
            float4 P[S];
#pragma unroll
            for (int s = 0; s < S; ++s) {
                int4 iv = ix[s];
                float4 w0 = lds4[iv.x], w1 = lds4[iv.y], w2 = lds4[iv.z], w3 = lds4[iv.w];
                float4 wm = f4min(f4min(w0, w1), f4min(w2, w3));
                float4 sum = f4add(f4add(f4e(wm, w0), f4e(wm, w1)),
                                   f4add(f4e(wm, w2), f4e(wm, w3)));
                P[s] = make_float4(wm.x - lg2(sum.x), wm.y - lg2(sum.y),
                                   wm.z - lg2(sum.z), wm.w - lg2(sum.w));
            }
            float4 pm = P[0];
#pragma unroll
            for (int s = 1; s < S; ++s) pm = f4max(pm, P[s]);
            float4 sm = make_float4(0.f, 0.f, 0.f, 0.f);
#pragma unroll
            for (int s = 0; s < S; ++s) sm = f4add(sm, f4e(P[s], pm));
            float4 qq = make_float4(pm.x + lg2(sm.x), pm.y + lg2(sm.y),
                                    pm.z + lg2(sm.z), pm.w + lg2(sm.w));
            qv[grp] = qq;
            lmax = fmaxf(lmax, fmaxf(fmaxf(qq.x, qq.y), fmaxf(qq.z, qq.w)));
        }

        // ---- m2: block reduce -> atomic -> per-clause 16-block spin ----
        {
            float m = lmax;
            for (int off = 32; off; off >>= 1) m = fmaxf(m, __shfl_down(m, off));
            if ((tid & 63) == 0) wred[tid >> 6] = m;
            __syncthreads();
            if (tid == 0) {
                float mm = wred[0];
#pragma unroll
                for (int i = 1; i < 16; ++i) mm = fmaxf(mm, wred[i]);
                atomicMax(m2k + step * C + c, f2key(mm));
                __hip_atomic_fetch_add(a16 + step * C + c, 1u,
                                       __ATOMIC_ACQ_REL, __HIP_MEMORY_SCOPE_AGENT);
                while (__hip_atomic_load(a16 + step * C + c, __ATOMIC_ACQUIRE,
                                         __HIP_MEMORY_SCOPE_AGENT) < 16u)
                    __builtin_amdgcn_s_sleep(1);
                unsigned k2 = __hip_atomic_load(m2k + step * C + c, __ATOMIC_ACQUIRE,
                                                __HIP_MEMORY_SCOPE_AGENT);
                shv = 1.0f / fmaxf(key2f(k2) * RKF, 1.0f);
            }
            __syncthreads();
        }
        const float qden = shv;

        // ---- merge: all operands in registers ----
        float lm3 = -3.0e38f;
#pragma unroll
        for (int grp = 0; grp < 2; ++grp) {
            float rv[4] = {sq[grp].x, sq[grp].y, sq[grp].z, sq[grp].w};
            float qa[4] = {qv[grp].x, qv[grp].y, qv[grp].z, qv[grp].w};
#pragma unroll
            for (int i = 0; i < 4; ++i) {
                float qx = qa[i] * qden;
                float hi = fmaxf(rv[i], qx), lo = fminf(rv[i], qx);
                float sv = hi + lg2(1.0f + ex2(lo - hi));     // softor2 (w-units)
                s3r[grp * 4 + i] = sv;
                lm3 = fmaxf(lm3, sv);
                if (step < STEPS - 1)
                    R[(size_t)(c * B + b0 + grp * 4 + i) * G + g] = sv;
            }
        }

        // ---- m3: block reduce -> atomic -> 256-block global barrier ----
        for (int off = 32; off; off >>= 1) lm3 = fmaxf(lm3, __shfl_down(lm3, off));
        __syncthreads();                 // wred reuse guard; also drains R stores
        if ((tid & 63) == 0) wred[tid >> 6] = lm3;
        __syncthreads();                 // (vmcnt(0) drain per __syncthreads semantics)
        if (tid == 0) {
            float mm = wred[0];
#pragma unroll
            for (int i = 1; i < 16; ++i) mm = fmaxf(mm, wred[i]);
            atomicMax(m3k + step, f2key(mm));
            __threadfence();             // agent release: R visible cross-XCD
            __hip_atomic_fetch_add(a256 + step, 1u,
                                   __ATOMIC_ACQ_REL, __HIP_MEMORY_SCOPE_AGENT);
            while (__hip_atomic_load(a256 + step, __ATOMIC_ACQUIRE,
                                     __HIP_MEMORY_SCOPE_AGENT) < 256u)
                __builtin_amdgcn_s_sleep(1);
            __threadfence();             // agent acquire: invalidate stale caches
            unsigned k3 = __hip_atomic_load(m3k + step, __ATOMIC_ACQUIRE,
                                            __HIP_MEMORY_SCOPE_AGENT);
            shv = key2f(k3) * RKF;
        }
        __syncthreads();
        float m3v = shv;
        ss = (step < STEPS - 1) ? 1.0f / fmaxf(m3v, 1.0f)    // next staging scale
                                : RKF  / fmaxf(m3v, 1.0f);   // final w->real scale
    }

    // final output (real units), coalesced dword stores
#pragma unroll
    for (int i8 = 0; i8 < 8; ++i8)
        outp[(size_t)(c * B + b0 + i8) * G + g] = s3r[i8] * ss;
}

extern "C" void kernel_launch(void* const* d_in, const int* in_sizes, int n_in,
                              void* d_out, int out_size, void* d_ws, size_t ws_size,
                              hipStream_t stream) {
    const float* x = (const float*)d_in[0];   // (B, G) fp32
    const int*   I = (const int*)d_in[1];     // (C, G, S, L) int32
    float* out = (float*)d_out;               // (C, B, G) fp32

    float* R = (float*)d_ws;                                             // N floats (w-units)
    unsigned* mk = (unsigned*)((char*)d_ws + (size_t)N * sizeof(float)); // 128 uints

    hipMemsetAsync(mk, 0, 128 * sizeof(unsigned), stream);
    k_all<<<256, 1024, 0, stream>>>(x, I, R, out, mk);
}

// Round 9
// 175.763 us; speedup vs baseline: 1.4639x; 1.4639x over previous
//
#include <hip/hip_runtime.h>

// ClauseInferModule: C=16, B=64, G=2048, S=8, L=4, 3 steps.
// Round-9 = round-6 per-step fused structure + round-7 NATIVE transcendentals.
// w-units: w = v*(1000/ln2) => exp((a-b)/gamma)==exp2(wa-wb), gamma*ln==log2 EXACT.
// All exp/log are raw v_exp_f32/v_log_f32 (libm exp2f/log2f are multi-instr
// OCML polys — proven 3x VALU bloat, r6 vs r7).
//
// k_step (one per scan step), grid=256 blocks x 1024 thr, block=(c,bchunk,ghalf):
//   clause: 4 rows b-interleaved in LDS (lds4[g] = b-quad * ss); one
//     ds_read_b128 gathers a literal for 4 b's; softand_L + two-pass softor_S.
//     q stays in REGISTERS (no q global traffic at all).
//   m2: block max -> device atomicMax -> per-clause 16-block arrival spin
//     (cheap: only atomics cross blocks; r6-proven. Co-residency guaranteed:
//     grid 256 <= capacity under any packing -> no deadlock).
//   merge: s3 = softor2(own staged quad, q/max(m2,1)) all in registers; writes
//     w-units R for the next step (kernel boundary = the R-visibility barrier).
//   m3: block max -> one device atomicMax per block (no wait on it here).
// k_scale: in-place out *= RKF/max(m3*RKF,1) (w -> real).
// softand renorm provably no-op (R<=1 invariant => softand<1 strictly).
// where(m>1,s/m,s) == s/max(m,1) exactly.

namespace {
constexpr int C = 16, B = 64, G = 2048, S = 8, L = 4;
constexpr int STEPS = 3;
constexpr int N  = C * B * G;
constexpr float KF  = 1442.6950408889634f;    // 1000/ln2 : real -> w
constexpr float RKF = 6.9314718055994531e-4f; // ln2/1000 : w -> real
}

__device__ __forceinline__ float ex2(float v) { return __builtin_amdgcn_exp2f(v); } // v_exp_f32
__device__ __forceinline__ float lg2(float v) { return __builtin_amdgcn_logf(v); }  // v_log_f32

__device__ __forceinline__ unsigned f2key(float f) {
    unsigned b = __float_as_uint(f);
    return (b & 0x80000000u) ? ~b : (b | 0x80000000u);
}
__device__ __forceinline__ float key2f(unsigned k) {
    return (k & 0x80000000u) ? __uint_as_float(k & 0x7fffffffu)
                             : __uint_as_float(~k);
}
__device__ __forceinline__ float4 f4min(float4 a, float4 b) {
    return make_float4(fminf(a.x,b.x), fminf(a.y,b.y), fminf(a.z,b.z), fminf(a.w,b.w));
}
__device__ __forceinline__ float4 f4max(float4 a, float4 b) {
    return make_float4(fmaxf(a.x,b.x), fmaxf(a.y,b.y), fmaxf(a.z,b.z), fmaxf(a.w,b.w));
}
__device__ __forceinline__ float4 f4e(float4 m, float4 v) {   // exp2(m - v), native
    return make_float4(ex2(m.x-v.x), ex2(m.y-v.y), ex2(m.z-v.z), ex2(m.w-v.w));
}
__device__ __forceinline__ float4 f4add(float4 a, float4 b) {
    return make_float4(a.x+b.x, a.y+b.y, a.z+b.z, a.w+b.w);
}

// mk layout (uints): [0..47] m2[step][c] | [48..50] m3[step] | [64..111] arr[step][c]

__global__ __launch_bounds__(1024, 4) void k_step(const float* __restrict__ src, int step0,
                                                  const int* __restrict__ I,
                                                  float* __restrict__ R,
                                                  unsigned* __restrict__ m2k,
                                                  const unsigned* __restrict__ m3prev,
                                                  unsigned* __restrict__ m3out,
                                                  unsigned* __restrict__ arr) {
    __shared__ float4 lds4[G];        // 32 KB: 4 rows b-interleaved, w-units scaled
    __shared__ float wred[16];
    __shared__ float shv;

    const int blk = blockIdx.x, tid = threadIdx.x;
    const int c = blk >> 4, bchunk = (blk >> 1) & 7, ghalf = blk & 1;
    const int g = ghalf * 1024 + tid, b0 = bchunk * 8;

    // register-cache this thread's 32 indices (b-independent)
    const int4* Ib = (const int4*)(I + (size_t)(c * G + g) * (S * L));
    int4 ix[S];
#pragma unroll
    for (int s = 0; s < S; ++s) ix[s] = Ib[s];

    const float ss = step0 ? KF : 1.0f / fmaxf(key2f(*m3prev) * RKF, 1.0f);
    const int rbase = step0 ? b0 : (c * B + b0);

    // preload group-0 rows: 4 rows, one float2 column per thread
    float2 pa[4];
#pragma unroll
    for (int j = 0; j < 4; ++j)
        pa[j] = ((const float2*)(src + (size_t)(rbase + j) * G))[tid];

    float4 qv[2], sq[2];
    float lmax = -3.0e38f;

#pragma unroll
    for (int grp = 0; grp < 2; ++grp) {
        if (grp) __syncthreads();          // group-0 gathers done before overwrite
        lds4[2*tid]   = make_float4(pa[0].x*ss, pa[1].x*ss, pa[2].x*ss, pa[3].x*ss);
        lds4[2*tid+1] = make_float4(pa[0].y*ss, pa[1].y*ss, pa[2].y*ss, pa[3].y*ss);
        if (grp == 0) {                    // prefetch group-1 rows; fly during compute
#pragma unroll
            for (int j = 0; j < 4; ++j)
                pa[j] = ((const float2*)(src + (size_t)(rbase + 4 + j) * G))[tid];
        }
        __syncthreads();                   // staging visible

        sq[grp] = lds4[g];                 // own src b-quad for merge phase

        // softand over L (component-wise on the b-quad), two-pass softor over S
        float4 P[S];
#pragma unroll
        for (int s = 0; s < S; ++s) {
            int4 iv = ix[s];
            float4 w0 = lds4[iv.x], w1 = lds4[iv.y], w2 = lds4[iv.z], w3 = lds4[iv.w];
            float4 wm = f4min(f4min(w0, w1), f4min(w2, w3));
            float4 sum = f4add(f4add(f4e(wm, w0), f4e(wm, w1)),
                               f4add(f4e(wm, w2), f4e(wm, w3)));
            P[s] = make_float4(wm.x - lg2(sum.x), wm.y - lg2(sum.y),
                               wm.z - lg2(sum.z), wm.w - lg2(sum.w));
        }
        float4 pm = P[0];
#pragma unroll
        for (int s = 1; s < S; ++s) pm = f4max(pm, P[s]);
        float4 sm = make_float4(0.f, 0.f, 0.f, 0.f);
#pragma unroll
        for (int s = 0; s < S; ++s) sm = f4add(sm, f4e(P[s], pm));
        float4 qq = make_float4(pm.x + lg2(sm.x), pm.y + lg2(sm.y),
                                pm.z + lg2(sm.z), pm.w + lg2(sm.w));
        qv[grp] = qq;
        lmax = fmaxf(lmax, fmaxf(fmaxf(qq.x, qq.y), fmaxf(qq.z, qq.w)));
    }

    // ---- m2: block reduce -> device atomic -> per-clause 16-block spin ----
    {
        float m = lmax;
        for (int off = 32; off; off >>= 1) m = fmaxf(m, __shfl_down(m, off));
        if ((tid & 63) == 0) wred[tid >> 6] = m;
        __syncthreads();
        if (tid == 0) {
            float mm = wred[0];
#pragma unroll
            for (int i = 1; i < 16; ++i) mm = fmaxf(mm, wred[i]);
            atomicMax(m2k + c, f2key(mm));
            __hip_atomic_fetch_add(arr + c, 1u,
                                   __ATOMIC_ACQ_REL, __HIP_MEMORY_SCOPE_AGENT);
            while (__hip_atomic_load(arr + c, __ATOMIC_ACQUIRE,
                                     __HIP_MEMORY_SCOPE_AGENT) < 16u)
                __builtin_amdgcn_s_sleep(1);
            unsigned k2 = __hip_atomic_load(m2k + c, __ATOMIC_ACQUIRE,
                                            __HIP_MEMORY_SCOPE_AGENT);
            shv = 1.0f / fmaxf(key2f(k2) * RKF, 1.0f);
        }
        __syncthreads();
    }
    const float qden = shv;

    // ---- merge: all operands in registers; write w-units R for next step ----
    float lm3 = -3.0e38f;
#pragma unroll
    for (int grp = 0; grp < 2; ++grp) {
        float rv[4] = {sq[grp].x, sq[grp].y, sq[grp].z, sq[grp].w};
        float qa[4] = {qv[grp].x, qv[grp].y, qv[grp].z, qv[grp].w};
#pragma unroll
        for (int i = 0; i < 4; ++i) {
            float qx = qa[i] * qden;
            float hi = fmaxf(rv[i], qx), lo = fminf(rv[i], qx);
            float sv = hi + lg2(1.0f + ex2(lo - hi));         // softor2 (w-units)
            R[(size_t)(c * B + b0 + grp * 4 + i) * G + g] = sv;
            lm3 = fmaxf(lm3, sv);
        }
    }
    // ---- m3: block reduce -> one device atomic per block (no wait) ----
    for (int off = 32; off; off >>= 1) lm3 = fmaxf(lm3, __shfl_down(lm3, off));
    __syncthreads();                       // wred reuse guard
    if ((tid & 63) == 0) wred[tid >> 6] = lm3;
    __syncthreads();
    if (tid == 0) {
        float mm = wred[0];
#pragma unroll
        for (int i = 1; i < 16; ++i) mm = fmaxf(mm, wred[i]);
        atomicMax(m3out, f2key(mm));
    }
}

// in-place: out(w-units) -> real, scaled by final m3 renorm.
__global__ __launch_bounds__(256) void k_scale(float* __restrict__ R,
                                               const unsigned* __restrict__ m3k) {
    float fs = RKF / fmaxf(key2f(*m3k) * RKF, 1.0f);
    int idx = blockIdx.x * 256 + threadIdx.x;
    float4 r = ((float4*)R)[idx];
    r.x *= fs; r.y *= fs; r.z *= fs; r.w *= fs;
    ((float4*)R)[idx] = r;
}

extern "C" void kernel_launch(void* const* d_in, const int* in_sizes, int n_in,
                              void* d_out, int out_size, void* d_ws, size_t ws_size,
                              hipStream_t stream) {
    const float* x = (const float*)d_in[0];   // (B, G) fp32
    const int*   I = (const int*)d_in[1];     // (C, G, S, L) int32
    float* out = (float*)d_out;               // (C, B, G) fp32 (w-units until k_scale)

    unsigned* mk = (unsigned*)d_ws;           // 128 uints

    hipMemsetAsync(mk, 0, 128 * sizeof(unsigned), stream);

    for (int step = 0; step < STEPS; ++step) {
        int step0 = (step == 0);
        const float* src = step0 ? x : out;
        unsigned* m2k = mk + step * C;
        unsigned* m3out = mk + 48 + step;
        const unsigned* m3prev = mk + 48 + (step ? step - 1 : 0);  // valid; unused if step0
        unsigned* arr = mk + 64 + step * C;
        k_step<<<256, 1024, 0, stream>>>(src, step0, I, out, m2k, m3prev, m3out, arr);
    }
    k_scale<<<N / 4 / 256, 256, 0, stream>>>(out, mk + 48 + STEPS - 1);
}